// Round 3
// baseline (1814.590 us; speedup 1.0000x reference)
//
#include <hip/hip_runtime.h>

typedef __bf16 bf16;
typedef __attribute__((ext_vector_type(8))) __bf16 bf16x8;
typedef __attribute__((ext_vector_type(4))) __bf16 bf16x4;
typedef __attribute__((ext_vector_type(4))) float f32x4;

#define B_ 4
#define T_ 2048
#define E_ 1024
#define H_ 16
#define KV_ 4
#define D_ 64
#define KVD_ 256
#define M_ 8192

#define MASK_NEG (-3.0e4f)   // finite sentinel: exp never sees huge-magnitude args
#define SCORE_CLAMP (2.0e4f)

// ---- 8-element loads -> bf16x8 fragment, overloaded on source dtype ----
__device__ inline bf16x8 load8(const bf16* p) { return *(const bf16x8*)p; }
__device__ inline bf16x8 load8(const float* p) {
  f32x4 a = *(const f32x4*)p;
  f32x4 b = *(const f32x4*)(p + 4);
  bf16x8 r;
#pragma unroll
  for (int j = 0; j < 4; ++j) { r[j] = (bf16)a[j]; r[4 + j] = (bf16)b[j]; }
  return r;
}

// ---------------- transpose+cast: WT[n][k] = bf16(W[k][n]), W is fp32 ----------------
__global__ __launch_bounds__(256) void transpose_k(const float* __restrict__ W,
                                                   bf16* __restrict__ WT,
                                                   int K, int N) {
  __shared__ bf16 tile[32][33];
  int k0 = blockIdx.x * 32, n0 = blockIdx.y * 32;
  int tr = threadIdx.x >> 5;  // 0..7
  int tc = threadIdx.x & 31;
#pragma unroll
  for (int i = 0; i < 32; i += 8)
    tile[tr + i][tc] = (bf16)W[(size_t)(k0 + tr + i) * N + n0 + tc];
  __syncthreads();
#pragma unroll
  for (int i = 0; i < 32; i += 8)
    WT[(size_t)(n0 + tr + i) * K + k0 + tc] = tile[tc][tr + i];
}

// ---------------- GEMM: C = (A @ W + bias) * scale ----------------
// A [M,K] (fp32 or bf16); WT [N,K] bf16; bias fp32; C [M,N] (bf16 or fp32).
// Tile 128(M) x 64(N), BK=32, 256 threads = 4 waves.
template <typename AT, typename CT>
__global__ __launch_bounds__(256) void gemm_bias_k(const AT* __restrict__ A,
                                                   const bf16* __restrict__ WT,
                                                   const float* __restrict__ bias,
                                                   CT* __restrict__ C,
                                                   int M, int N, int K, float scale) {
  const int m0 = blockIdx.x * 128;
  const int n0 = blockIdx.y * 64;
  const int tid = threadIdx.x;
  const int wave = tid >> 6;
  const int lane = tid & 63;
  const int fr = lane & 15;  // frag row (A) / frag col (B)
  const int q = lane >> 4;   // quad -> k-group

  __shared__ bf16 lB[64][48];  // [n][k], pad 32->48: 16B align + bank spread

  f32x4 acc[2][4] = {};

  const AT* Arow0 = A + (size_t)(m0 + wave * 16 + fr) * K + q * 8;
  const AT* Arow1 = Arow0 + (size_t)64 * K;

  const int snn = tid >> 2;        // 0..63  (n within tile)
  const int skc = (tid & 3) << 3;  // 0,8,16,24 (k chunk)
  const bf16* Brow = WT + (size_t)(n0 + snn) * K + skc;

  bf16x8 bstage = *(const bf16x8*)(Brow);
  bf16x8 a0 = load8(Arow0);
  bf16x8 a1 = load8(Arow1);

  for (int k0 = 0; k0 < K; k0 += 32) {
    *(bf16x8*)(&lB[snn][skc]) = bstage;
    __syncthreads();
    bf16x8 af0 = a0, af1 = a1;
    if (k0 + 32 < K) {  // prefetch next tiles while MFMAs run
      bstage = *(const bf16x8*)(Brow + k0 + 32);
      a0 = load8(Arow0 + k0 + 32);
      a1 = load8(Arow1 + k0 + 32);
    }
#pragma unroll
    for (int nt = 0; nt < 4; ++nt) {
      bf16x8 bf = *(const bf16x8*)(&lB[nt * 16 + fr][q * 8]);
      acc[0][nt] = __builtin_amdgcn_mfma_f32_16x16x32_bf16(af0, bf, acc[0][nt], 0, 0, 0);
      acc[1][nt] = __builtin_amdgcn_mfma_f32_16x16x32_bf16(af1, bf, acc[1][nt], 0, 0, 0);
    }
    __syncthreads();
  }

#pragma unroll
  for (int nt = 0; nt < 4; ++nt) {
    int col = n0 + nt * 16 + fr;
    float bv = bias[col];
#pragma unroll
    for (int mt = 0; mt < 2; ++mt) {
#pragma unroll
      for (int i = 0; i < 4; ++i) {
        int row = m0 + mt * 64 + wave * 16 + q * 4 + i;
        C[(size_t)row * N + col] = (CT)((acc[mt][nt][i] + bv) * scale);
      }
    }
  }
}

// ---------------- flash attention (vector ALU, online softmax) ----------------
// Grid (32, 16, 4) = (q-block, head, batch); 256 threads.
// Thread t owns query row qr=t/4 (scores for keys kk==c mod 4, c=t&3)
// and output dims d = c*16 .. c*16+15.
__global__ __launch_bounds__(256) void attn_k(const bf16* __restrict__ Qg,
                                              const bf16* __restrict__ Kg,
                                              const bf16* __restrict__ Vg,
                                              bf16* __restrict__ Og) {
  const int qb = gridDim.x - 1 - blockIdx.x;  // longest blocks dispatch first
  const int h = blockIdx.y;
  const int b = blockIdx.z;
  const int kv = h >> 2;  // G = 4
  const int tid = threadIdx.x;
  const int qr = tid >> 2;
  const int c = tid & 3;

  __shared__ bf16 Qs[64][72];   // 9216 B
  __shared__ float Ks[64][68];  // 17408 B
  __shared__ float Vs[64][68];  // 17408 B
  __shared__ float Ps[64][68];  // 17408 B  -> 61440 B total

  {  // stage Q block (already scaled by 1/8 in projection)
    const bf16* src = Qg + (size_t)(b * T_ + qb * 64 + qr) * E_ + h * 64 + c * 16;
    *(bf16x8*)(&Qs[qr][c * 16]) = *(const bf16x8*)(src);
    *(bf16x8*)(&Qs[qr][c * 16 + 8]) = *(const bf16x8*)(src + 8);
  }

  float Oacc[16];
#pragma unroll
  for (int j = 0; j < 16; ++j) Oacc[j] = 0.f;
  float m_run = MASK_NEG, l_run = 0.f;

  const int gq = qb * 64 + qr;
  const int nkb = qb + 1;
  for (int kb = 0; kb < nkb; ++kb) {
    __syncthreads();  // previous PV done with Vs/Ps
    {                 // stage K,V rows (fp32 in LDS)
      const bf16* ksrc = Kg + (size_t)(b * T_ + kb * 64 + qr) * KVD_ + kv * 64 + c * 16;
      const bf16* vsrc = Vg + (size_t)(b * T_ + kb * 64 + qr) * KVD_ + kv * 64 + c * 16;
      bf16x8 k0 = *(const bf16x8*)(ksrc);
      bf16x8 k1 = *(const bf16x8*)(ksrc + 8);
      bf16x8 v0 = *(const bf16x8*)(vsrc);
      bf16x8 v1 = *(const bf16x8*)(vsrc + 8);
#pragma unroll
      for (int j = 0; j < 8; ++j) {
        Ks[qr][c * 16 + j] = (float)k0[j];
        Ks[qr][c * 16 + 8 + j] = (float)k1[j];
        Vs[qr][c * 16 + j] = (float)v0[j];
        Vs[qr][c * 16 + 8 + j] = (float)v1[j];
      }
    }
    __syncthreads();

    // scores s[j] for keys kk = c + 4j
    float s[16];
#pragma unroll
    for (int j = 0; j < 16; ++j) s[j] = 0.f;
    for (int dc = 0; dc < 64; dc += 4) {
      bf16x4 qv = *(const bf16x4*)(&Qs[qr][dc]);
      float q0 = (float)qv[0], q1 = (float)qv[1], q2 = (float)qv[2], q3 = (float)qv[3];
#pragma unroll
      for (int j = 0; j < 16; ++j) {
        f32x4 kvv = *(const f32x4*)(&Ks[c + 4 * j][dc]);
        s[j] += q0 * kvv[0] + q1 * kvv[1] + q2 * kvv[2] + q3 * kvv[3];
      }
    }

#pragma unroll
    for (int j = 0; j < 16; ++j) {
      s[j] = fminf(fmaxf(s[j], -SCORE_CLAMP), SCORE_CLAMP);
      int gk = kb * 64 + c + 4 * j;
      if (gk > gq) s[j] = MASK_NEG;  // causal mask (>=1 valid key always in-range)
    }
    float mb = s[0];
#pragma unroll
    for (int j = 1; j < 16; ++j) mb = fmaxf(mb, s[j]);
    mb = fmaxf(mb, __shfl_xor(mb, 1, 64));
    mb = fmaxf(mb, __shfl_xor(mb, 2, 64));
    float m_new = fmaxf(m_run, mb);       // bounded
    float alpha = __expf(m_run - m_new);  // arg <= 0
    float psum = 0.f;
#pragma unroll
    for (int j = 0; j < 16; ++j) {
      float p = __expf(s[j] - m_new);  // arg <= 0 -> p in [0,1]
      psum += p;
      Ps[qr][c + 4 * j] = p;
    }
    psum += __shfl_xor(psum, 1, 64);
    psum += __shfl_xor(psum, 2, 64);
    l_run = l_run * alpha + psum;
    m_run = m_new;
#pragma unroll
    for (int j = 0; j < 16; ++j) Oacc[j] *= alpha;
    __syncthreads();  // Ps visible

    // PV: O[qr][d-slice] += P[qr][kk] * V[kk][d-slice]
    for (int kk = 0; kk < 64; kk += 4) {
      f32x4 pv = *(const f32x4*)(&Ps[qr][kk]);
#pragma unroll
      for (int u = 0; u < 4; ++u) {
        float p = pv[u];
        f32x4 va = *(const f32x4*)(&Vs[kk + u][c * 16]);
        f32x4 vb = *(const f32x4*)(&Vs[kk + u][c * 16 + 4]);
        f32x4 vc = *(const f32x4*)(&Vs[kk + u][c * 16 + 8]);
        f32x4 vd = *(const f32x4*)(&Vs[kk + u][c * 16 + 12]);
#pragma unroll
        for (int j = 0; j < 4; ++j) {
          Oacc[j] += p * va[j];
          Oacc[4 + j] += p * vb[j];
          Oacc[8 + j] += p * vc[j];
          Oacc[12 + j] += p * vd[j];
        }
      }
    }
  }

  float inv = 1.f / fmaxf(l_run, 1e-30f);
  bf16x8 o0, o1;
#pragma unroll
  for (int j = 0; j < 8; ++j) {
    o0[j] = (bf16)(Oacc[j] * inv);
    o1[j] = (bf16)(Oacc[8 + j] * inv);
  }
  bf16* dst = Og + (size_t)(b * T_ + qb * 64 + qr) * E_ + h * 64 + c * 16;
  *(bf16x8*)(dst) = o0;
  *(bf16x8*)(dst + 8) = o1;
}

extern "C" void kernel_launch(void* const* d_in, const int* in_sizes, int n_in,
                              void* d_out, int out_size, void* d_ws, size_t ws_size,
                              hipStream_t stream) {
  (void)in_sizes; (void)n_in; (void)out_size; (void)ws_size;
  // Reference dtypes are float32 for ALL inputs and the output.
  const float* hidden = (const float*)d_in[0];
  // d_in[1] = attention_mask: deterministically causal -> applied analytically
  const float* Wq = (const float*)d_in[2];
  const float* bq = (const float*)d_in[3];
  const float* Wk = (const float*)d_in[4];
  const float* bk = (const float*)d_in[5];
  const float* Wv = (const float*)d_in[6];
  const float* bv = (const float*)d_in[7];
  const float* Wo = (const float*)d_in[8];
  const float* bo = (const float*)d_in[9];
  float* out = (float*)d_out;

  char* ws = (char*)d_ws;
  bf16* WqT = (bf16*)(ws);                                    // 2 MB
  bf16* WkT = (bf16*)(ws + (2u << 20));                       // 512 KB
  bf16* WvT = (bf16*)(ws + (2u << 20) + (512u << 10));        // 512 KB
  bf16* WoT = (bf16*)(ws + (3u << 20));                       // 2 MB
  bf16* Qb  = (bf16*)(ws + (5u << 20));                       // 16 MB
  bf16* Kb  = (bf16*)(ws + (21u << 20));                      // 4 MB
  bf16* Vb  = (bf16*)(ws + (25u << 20));                      // 4 MB
  bf16* Ab  = (bf16*)(ws + (29u << 20));                      // 16 MB -> 45 MB total

  transpose_k<<<dim3(32, 32), 256, 0, stream>>>(Wq, WqT, 1024, 1024);
  transpose_k<<<dim3(32, 8), 256, 0, stream>>>(Wk, WkT, 1024, 256);
  transpose_k<<<dim3(32, 8), 256, 0, stream>>>(Wv, WvT, 1024, 256);
  transpose_k<<<dim3(32, 32), 256, 0, stream>>>(Wo, WoT, 1024, 1024);

  // q = (x@Wq + bq) * D^-0.5   (scale folded into epilogue)
  gemm_bias_k<float, bf16><<<dim3(64, 16), 256, 0, stream>>>(hidden, WqT, bq, Qb, M_, E_, E_, 0.125f);
  gemm_bias_k<float, bf16><<<dim3(64, 4), 256, 0, stream>>>(hidden, WkT, bk, Kb, M_, KVD_, E_, 1.0f);
  gemm_bias_k<float, bf16><<<dim3(64, 4), 256, 0, stream>>>(hidden, WvT, bv, Vb, M_, KVD_, E_, 1.0f);

  attn_k<<<dim3(32, 16, 4), 256, 0, stream>>>(Qb, Kb, Vb, Ab);

  gemm_bias_k<bf16, float><<<dim3(64, 16), 256, 0, stream>>>(Ab, WoT, bo, out, M_, E_, E_, 1.0f);
}

// Round 4
// 543.357 us; speedup vs baseline: 3.3396x; 3.3396x over previous
//
#include <hip/hip_runtime.h>

typedef __bf16 bf16;
typedef __attribute__((ext_vector_type(8))) __bf16 bf16x8;
typedef __attribute__((ext_vector_type(4))) float f32x4;

#define B_ 4
#define T_ 2048
#define E_ 1024
#define H_ 16
#define KV_ 4
#define D_ 64
#define KVD_ 256
#define M_ 8192

#define MASK_NEG (-3.0e4f)  // finite sentinel: exp args stay bounded

// ---- 8-element loads -> bf16x8 fragment, overloaded on source dtype ----
__device__ inline bf16x8 load8(const bf16* p) { return *(const bf16x8*)p; }
__device__ inline bf16x8 load8(const float* p) {
  f32x4 a = *(const f32x4*)p;
  f32x4 b = *(const f32x4*)(p + 4);
  bf16x8 r;
#pragma unroll
  for (int j = 0; j < 4; ++j) { r[j] = (bf16)a[j]; r[4 + j] = (bf16)b[j]; }
  return r;
}

// ---------------- transpose+cast: WT[n][k] = bf16(W[k][n]), W is fp32 ----------------
__global__ __launch_bounds__(256) void transpose_k(const float* __restrict__ W,
                                                   bf16* __restrict__ WT,
                                                   int K, int N) {
  __shared__ bf16 tile[32][33];
  int k0 = blockIdx.x * 32, n0 = blockIdx.y * 32;
  int tr = threadIdx.x >> 5;  // 0..7
  int tc = threadIdx.x & 31;
#pragma unroll
  for (int i = 0; i < 32; i += 8)
    tile[tr + i][tc] = (bf16)W[(size_t)(k0 + tr + i) * N + n0 + tc];
  __syncthreads();
#pragma unroll
  for (int i = 0; i < 32; i += 8)
    WT[(size_t)(n0 + tr + i) * K + k0 + tc] = tile[tc][tr + i];
}

// ---------------- GEMM: C = (A @ W + bias) * scale ----------------
// A [M,K] (fp32 or bf16); WT [N,K] bf16; bias fp32; C [M,N] (bf16 or fp32).
// Tile 128(M) x 64(N), BK=32, 256 threads = 4 waves.
template <typename AT, typename CT>
__global__ __launch_bounds__(256) void gemm_bias_k(const AT* __restrict__ A,
                                                   const bf16* __restrict__ WT,
                                                   const float* __restrict__ bias,
                                                   CT* __restrict__ C,
                                                   int M, int N, int K, float scale) {
  const int m0 = blockIdx.x * 128;
  const int n0 = blockIdx.y * 64;
  const int tid = threadIdx.x;
  const int wave = tid >> 6;
  const int lane = tid & 63;
  const int fr = lane & 15;  // frag row (A) / frag col (B)
  const int q = lane >> 4;   // quad -> k-group

  __shared__ bf16 lB[64][48];  // [n][k], pad 32->48: 16B align + bank spread

  f32x4 acc[2][4] = {};

  const AT* Arow0 = A + (size_t)(m0 + wave * 16 + fr) * K + q * 8;
  const AT* Arow1 = Arow0 + (size_t)64 * K;

  const int snn = tid >> 2;        // 0..63  (n within tile)
  const int skc = (tid & 3) << 3;  // 0,8,16,24 (k chunk)
  const bf16* Brow = WT + (size_t)(n0 + snn) * K + skc;

  bf16x8 bstage = *(const bf16x8*)(Brow);
  bf16x8 a0 = load8(Arow0);
  bf16x8 a1 = load8(Arow1);

  for (int k0 = 0; k0 < K; k0 += 32) {
    *(bf16x8*)(&lB[snn][skc]) = bstage;
    __syncthreads();
    bf16x8 af0 = a0, af1 = a1;
    if (k0 + 32 < K) {  // prefetch next tiles while MFMAs run
      bstage = *(const bf16x8*)(Brow + k0 + 32);
      a0 = load8(Arow0 + k0 + 32);
      a1 = load8(Arow1 + k0 + 32);
    }
#pragma unroll
    for (int nt = 0; nt < 4; ++nt) {
      bf16x8 bf = *(const bf16x8*)(&lB[nt * 16 + fr][q * 8]);
      acc[0][nt] = __builtin_amdgcn_mfma_f32_16x16x32_bf16(af0, bf, acc[0][nt], 0, 0, 0);
      acc[1][nt] = __builtin_amdgcn_mfma_f32_16x16x32_bf16(af1, bf, acc[1][nt], 0, 0, 0);
    }
    __syncthreads();
  }

#pragma unroll
  for (int nt = 0; nt < 4; ++nt) {
    int col = n0 + nt * 16 + fr;
    float bv = bias[col];
#pragma unroll
    for (int mt = 0; mt < 2; ++mt) {
#pragma unroll
      for (int i = 0; i < 4; ++i) {
        int row = m0 + mt * 64 + wave * 16 + q * 4 + i;
        C[(size_t)row * N + col] = (CT)((acc[mt][nt][i] + bv) * scale);
      }
    }
  }
}

// ---------------- MFMA flash attention ----------------
// Grid (32, 16, 4) = (q-block, head, batch); 256 threads = 4 waves.
// Block handles 64 queries; wave w owns q-rows w*16..w*16+15.
// QK^T and PV on 16x16x32 bf16 MFMA. P round-trips through LDS
// (C-layout -> A-layout transform). Only diagonal key-block is masked.
__global__ __launch_bounds__(256) void attn_k(const bf16* __restrict__ Qg,
                                              const bf16* __restrict__ Kg,
                                              const bf16* __restrict__ Vg,
                                              bf16* __restrict__ Og) {
  const int qb = gridDim.x - 1 - blockIdx.x;  // longest blocks dispatch first
  const int h = blockIdx.y;
  const int b = blockIdx.z;
  const int kv = h >> 2;  // G = 4
  const int tid = threadIdx.x;
  const int wave = tid >> 6;
  const int lane = tid & 63;
  const int fr = lane & 15;
  const int quad = lane >> 4;

  __shared__ bf16 Ks[64][72];  // [key][d]   9216 B
  __shared__ bf16 Vt[64][72];  // [d][key]   9216 B
  __shared__ bf16 Ps[64][72];  // [q][key]   9216 B  -> 27648 total

  // Q A-fragments, held in registers for the whole kernel.
  // A[m=fr][k=quad*8+j + 32*kc], m -> global q row qb*64 + wave*16 + fr.
  bf16x8 qa[2];
  {
    const bf16* qsrc = Qg + (size_t)(b * T_ + qb * 64 + wave * 16 + fr) * E_ + h * 64 + quad * 8;
    qa[0] = *(const bf16x8*)(qsrc);
    qa[1] = *(const bf16x8*)(qsrc + 32);
  }

  f32x4 Oacc[4] = {};  // C-layout: row quad*4+i, col dt*16+fr
  float m_run[4], l_run[4];
#pragma unroll
  for (int i = 0; i < 4; ++i) { m_run[i] = MASK_NEG; l_run[i] = 0.f; }

  const int skey = tid & 63;       // staging: key row (== lane)
  const int sdc = (tid >> 6) * 16; // staging: d column base (== wave*16)

  for (int kb = 0; kb <= qb; ++kb) {
    __syncthreads();  // prior PV done with Vt/Ks
    {
      const bf16* ksrc = Kg + (size_t)(b * T_ + kb * 64 + skey) * KVD_ + kv * 64 + sdc;
      const bf16* vsrc = Vg + (size_t)(b * T_ + kb * 64 + skey) * KVD_ + kv * 64 + sdc;
      bf16x8 k0 = *(const bf16x8*)(ksrc);
      bf16x8 k1 = *(const bf16x8*)(ksrc + 8);
      bf16x8 v0 = *(const bf16x8*)(vsrc);
      bf16x8 v1 = *(const bf16x8*)(vsrc + 8);
      *(bf16x8*)(&Ks[skey][sdc]) = k0;
      *(bf16x8*)(&Ks[skey][sdc + 8]) = k1;
#pragma unroll
      for (int j = 0; j < 8; ++j) {  // V transpose scatter
        Vt[sdc + j][skey] = v0[j];
        Vt[sdc + 8 + j][skey] = v1[j];
      }
    }
    __syncthreads();

    // ---- QK^T: S[m=q][n=key], B[k=d][n=key] = Ks[n][k] (row-major b128) ----
    f32x4 S[4] = {};
#pragma unroll
    for (int nt = 0; nt < 4; ++nt) {
#pragma unroll
      for (int kc = 0; kc < 2; ++kc) {
        bf16x8 kf = *(const bf16x8*)(&Ks[nt * 16 + fr][kc * 32 + quad * 8]);
        S[nt] = __builtin_amdgcn_mfma_f32_16x16x32_bf16(qa[kc], kf, S[nt], 0, 0, 0);
      }
    }

    if (kb == qb) {  // causal mask, diagonal block only
#pragma unroll
      for (int nt = 0; nt < 4; ++nt) {
        int colk = nt * 16 + fr;
#pragma unroll
        for (int i = 0; i < 4; ++i) {
          int rowq = wave * 16 + quad * 4 + i;
          if (colk > rowq) S[nt][i] = MASK_NEG;
        }
      }
    }

    // ---- online softmax; rows quad*4+i, reduce over the 16 fr-lanes ----
    float alpha[4];
#pragma unroll
    for (int i = 0; i < 4; ++i) {
      float mb = fmaxf(fmaxf(S[0][i], S[1][i]), fmaxf(S[2][i], S[3][i]));
      mb = fmaxf(mb, __shfl_xor(mb, 1, 64));
      mb = fmaxf(mb, __shfl_xor(mb, 2, 64));
      mb = fmaxf(mb, __shfl_xor(mb, 4, 64));
      mb = fmaxf(mb, __shfl_xor(mb, 8, 64));
      float mn = fmaxf(m_run[i], mb);
      alpha[i] = __expf(m_run[i] - mn);
      m_run[i] = mn;
      float ps = 0.f;
#pragma unroll
      for (int nt = 0; nt < 4; ++nt) {
        float p = __expf(S[nt][i] - mn);  // arg <= 0
        S[nt][i] = p;
        ps += p;
      }
      ps += __shfl_xor(ps, 1, 64);
      ps += __shfl_xor(ps, 2, 64);
      ps += __shfl_xor(ps, 4, 64);
      ps += __shfl_xor(ps, 8, 64);
      l_run[i] = l_run[i] * alpha[i] + ps;
    }
#pragma unroll
    for (int dt = 0; dt < 4; ++dt)
#pragma unroll
      for (int i = 0; i < 4; ++i) Oacc[dt][i] *= alpha[i];

    // ---- P (C-layout) -> LDS; each wave writes only its own 16 rows ----
#pragma unroll
    for (int nt = 0; nt < 4; ++nt)
#pragma unroll
      for (int i = 0; i < 4; ++i)
        Ps[wave * 16 + quad * 4 + i][nt * 16 + fr] = (bf16)S[nt][i];
    __syncthreads();  // also covers Vt reads below vs next staging

    // ---- PV: A = P rows of this wave; B[k=key][n=d] = Vt[n][k] ----
    bf16x8 pa[2];
    pa[0] = *(const bf16x8*)(&Ps[wave * 16 + fr][quad * 8]);
    pa[1] = *(const bf16x8*)(&Ps[wave * 16 + fr][32 + quad * 8]);
#pragma unroll
    for (int dt = 0; dt < 4; ++dt) {
#pragma unroll
      for (int kc = 0; kc < 2; ++kc) {
        bf16x8 vf = *(const bf16x8*)(&Vt[dt * 16 + fr][kc * 32 + quad * 8]);
        Oacc[dt] = __builtin_amdgcn_mfma_f32_16x16x32_bf16(pa[kc], vf, Oacc[dt], 0, 0, 0);
      }
    }
  }

  // ---- epilogue: O /= l, write bf16 ----
#pragma unroll
  for (int i = 0; i < 4; ++i) {
    float inv = 1.f / fmaxf(l_run[i], 1e-30f);
    bf16* dst = Og + (size_t)(b * T_ + qb * 64 + wave * 16 + quad * 4 + i) * E_ + h * 64;
#pragma unroll
    for (int dt = 0; dt < 4; ++dt)
      dst[dt * 16 + fr] = (bf16)(Oacc[dt][i] * inv);
  }
}

extern "C" void kernel_launch(void* const* d_in, const int* in_sizes, int n_in,
                              void* d_out, int out_size, void* d_ws, size_t ws_size,
                              hipStream_t stream) {
  (void)in_sizes; (void)n_in; (void)out_size; (void)ws_size;
  // Reference dtypes are float32 for ALL inputs and the output.
  const float* hidden = (const float*)d_in[0];
  // d_in[1] = attention_mask: deterministically causal -> applied analytically
  const float* Wq = (const float*)d_in[2];
  const float* bq = (const float*)d_in[3];
  const float* Wk = (const float*)d_in[4];
  const float* bk = (const float*)d_in[5];
  const float* Wv = (const float*)d_in[6];
  const float* bv = (const float*)d_in[7];
  const float* Wo = (const float*)d_in[8];
  const float* bo = (const float*)d_in[9];
  float* out = (float*)d_out;

  char* ws = (char*)d_ws;
  bf16* WqT = (bf16*)(ws);                                    // 2 MB
  bf16* WkT = (bf16*)(ws + (2u << 20));                       // 512 KB
  bf16* WvT = (bf16*)(ws + (2u << 20) + (512u << 10));        // 512 KB
  bf16* WoT = (bf16*)(ws + (3u << 20));                       // 2 MB
  bf16* Qb  = (bf16*)(ws + (5u << 20));                       // 16 MB
  bf16* Kb  = (bf16*)(ws + (21u << 20));                      // 4 MB
  bf16* Vb  = (bf16*)(ws + (25u << 20));                      // 4 MB
  bf16* Ab  = (bf16*)(ws + (29u << 20));                      // 16 MB -> 45 MB total

  transpose_k<<<dim3(32, 32), 256, 0, stream>>>(Wq, WqT, 1024, 1024);
  transpose_k<<<dim3(32, 8), 256, 0, stream>>>(Wk, WkT, 1024, 256);
  transpose_k<<<dim3(32, 8), 256, 0, stream>>>(Wv, WvT, 1024, 256);
  transpose_k<<<dim3(32, 32), 256, 0, stream>>>(Wo, WoT, 1024, 1024);

  // q = (x@Wq + bq) * D^-0.5   (scale folded into epilogue)
  gemm_bias_k<float, bf16><<<dim3(64, 16), 256, 0, stream>>>(hidden, WqT, bq, Qb, M_, E_, E_, 0.125f);
  gemm_bias_k<float, bf16><<<dim3(64, 4), 256, 0, stream>>>(hidden, WkT, bk, Kb, M_, KVD_, E_, 1.0f);
  gemm_bias_k<float, bf16><<<dim3(64, 4), 256, 0, stream>>>(hidden, WvT, bv, Vb, M_, KVD_, E_, 1.0f);

  attn_k<<<dim3(32, 16, 4), 256, 0, stream>>>(Qb, Kb, Vb, Ab);

  gemm_bias_k<bf16, float><<<dim3(64, 16), 256, 0, stream>>>(Ab, WoT, bo, out, M_, E_, E_, 1.0f);
}